// Round 12
// baseline (198.484 us; speedup 1.0000x reference)
//
#include <hip/hip_runtime.h>
#include <hip/hip_bf16.h>

#define LN_EPS 1e-5f
#define SLOPE 0.01f

typedef short bf16x8 __attribute__((ext_vector_type(8)));
typedef float f32x4 __attribute__((ext_vector_type(4)));

// ---------------------------------------------------------------------------
// Kernel 1 (convert): all-bf16 operand prep, 556 blocks x 256 thr
//  blocks 0..199:   W1 -> W1Ft/W1Fb fragment-major
//  blocks 200..299: W2 -> W2F fragment-major
//  blocks 300..555: AcatU/AcatV = [bf16(robot|object) | bf16(lang)]
// ---------------------------------------------------------------------------
__global__ __launch_bounds__(256) void convert_kernel(
    const float* __restrict__ robot, const float* __restrict__ object,
    const float* __restrict__ lang, const float* __restrict__ W1,
    const float* __restrict__ W2,
    __hip_bfloat16* __restrict__ AcatU, __hip_bfloat16* __restrict__ AcatV,
    __hip_bfloat16* __restrict__ W1Ft, __hip_bfloat16* __restrict__ W1Fb,
    __hip_bfloat16* __restrict__ W2F)
{
  __shared__ float tile[32][33];
  const int bx = blockIdx.x;
  const int tid = threadIdx.x;

  if (bx < 300) {
    int kk, d0;
    const float* srcbase;
    __hip_bfloat16* dstbase;
    if (bx < 200) {
      kk = bx / 10; d0 = (bx % 10) * 32;
      srcbase = W1 + (size_t)(kk * 32) * 320;
      dstbase = (kk < 10) ? W1Ft : W1Fb;
      if (kk >= 10) kk -= 10;
    } else {
      const int t = bx - 200;
      kk = t / 10; d0 = (t % 10) * 32;
      srcbase = W2 + (size_t)(kk * 32) * 320;
      dstbase = W2F;
    }
    const int tx = tid & 31, ty = tid >> 5;  // ty 0..7
#pragma unroll
    for (int r = 0; r < 32; r += 8)
      tile[ty + r][tx] = srcbase[(ty + r) * 320 + d0 + tx];
    __syncthreads();
    const int fl   = tid >> 7;        // frag_local 0..1
    const int l    = (tid >> 1) & 63; // lane
    const int half = tid & 1;
    const int frag = (d0 >> 4) + fl;
    __hip_bfloat16* dst = dstbase + ((kk * 20 + frag) * 512) + l * 8 + half * 4;
#pragma unroll
    for (int e = 0; e < 4; ++e)
      dst[e] = __float2bfloat16(tile[(l >> 4) * 8 + half * 4 + e]
                                    [fl * 16 + (l & 15)]);
  } else {
    const int i0 = (bx - 300) * 2;
#pragma unroll
    for (int rr = 0; rr < 2; ++rr) {
      const int i = i0 + rr;
      AcatU[i * 320 + tid] = __float2bfloat16(robot[i * 256 + tid]);
      AcatV[i * 320 + tid] = __float2bfloat16(object[i * 256 + tid]);
      if (tid < 64) {
        const __hip_bfloat16 lv = __float2bfloat16(lang[tid]);
        AcatU[i * 320 + 256 + tid] = lv;
        AcatV[i * 320 + 256 + tid] = lv;
      }
    }
  }
}

// ---------------------------------------------------------------------------
// Kernel 2 (prep_gemm): U = AcatU @ W1t, V = AcatV @ W1b + b1 (MFMA).
// Unchanged from round 11 (proven). grid (8 i-tiles, 2 uv).
// ---------------------------------------------------------------------------
__global__ __launch_bounds__(256, 3) void prep_gemm(
    const __hip_bfloat16* __restrict__ AcatU,
    const __hip_bfloat16* __restrict__ AcatV,
    const __hip_bfloat16* __restrict__ W1Ft,
    const __hip_bfloat16* __restrict__ W1Fb,
    const float* __restrict__ b1,
    float* __restrict__ U, float* __restrict__ V,
    __hip_bfloat16* __restrict__ Ub, __hip_bfloat16* __restrict__ VbF,
    float* __restrict__ stats)
{
  __shared__ __align__(16) __hip_bfloat16 hA[64 * 320];
  __shared__ float s4[64][5], q4[64][5];

  const int it = blockIdx.x, uv = blockIdx.y;
  const int i0 = it * 64;
  const int tid = threadIdx.x;
  const int lane = tid & 63;
  const int w    = tid >> 6;
  const int r16  = lane & 15;
  const int g    = lane >> 4;
  const int row  = tid >> 2;
  const int seg  = tid & 3;

  const __hip_bfloat16* __restrict__ Acat = uv ? AcatV : AcatU;
  const __hip_bfloat16* __restrict__ W1F  = uv ? W1Fb : W1Ft;

  {
    const __hip_bfloat16* __restrict__ src =
        Acat + (size_t)(i0 + row) * 320 + seg * 80;
    const unsigned swz  = (unsigned)((row & 7) << 4);
    const unsigned base = (unsigned)row * 640u + (unsigned)seg * 160u;
#pragma unroll
    for (int m = 0; m < 10; ++m) {
      const bf16x8 v = *(const bf16x8*)(src + m * 8);
      *(bf16x8*)((char*)hA + ((base + (unsigned)m * 16u) ^ swz)) = v;
    }
  }

  const int wc = w;
  const __hip_bfloat16* __restrict__ Bf = W1F + (size_t)(wc * 5) * 512 + lane * 8;
  bf16x8 bbuf[2][5];
#pragma unroll
  for (int nf = 0; nf < 5; ++nf)
    bbuf[0][nf] = *(const bf16x8*)(Bf + nf * 512);

  __syncthreads();

  f32x4 acc[4][5];
#pragma unroll
  for (int mf = 0; mf < 4; ++mf)
#pragma unroll
    for (int nf = 0; nf < 5; ++nf)
      acc[mf][nf] = (f32x4){0.f, 0.f, 0.f, 0.f};

  const unsigned swzA = (unsigned)((r16 & 7) << 4);
  unsigned arow[4];
#pragma unroll
  for (int mf = 0; mf < 4; ++mf)
    arow[mf] = (unsigned)(mf * 16 + r16) * 640u;

#pragma unroll
  for (int kk = 0; kk < 10; ++kk) {
    const int cur = kk & 1, nxt = cur ^ 1;
    if (kk < 9) {
#pragma unroll
      for (int nf = 0; nf < 5; ++nf)
        bbuf[nxt][nf] = *(const bf16x8*)(Bf + ((kk + 1) * 20 + nf) * 512);
    }
    const unsigned k2 = (unsigned)((kk * 32 + g * 8) * 2);
    bf16x8 a[4];
#pragma unroll
    for (int mf = 0; mf < 4; ++mf)
      a[mf] = *(const bf16x8*)((const char*)hA + ((arow[mf] + k2) ^ swzA));
#pragma unroll
    for (int nf = 0; nf < 5; ++nf)
#pragma unroll
      for (int mf = 0; mf < 4; ++mf)
        acc[mf][nf] = __builtin_amdgcn_mfma_f32_16x16x32_bf16(
            a[mf], bbuf[cur][nf], acc[mf][nf], 0, 0, 0);
  }

  float b1c[5];
#pragma unroll
  for (int nf = 0; nf < 5; ++nf)
    b1c[nf] = uv ? b1[wc * 80 + nf * 16 + r16] : 0.f;

  float* scr = (float*)hA;
  __syncthreads();

#pragma unroll
  for (int mf = 0; mf < 4; ++mf) {
#pragma unroll
    for (int r = 0; r < 4; ++r) {
      const int j = i0 + mf * 16 + g * 4 + r;
      float s = 0.f, q = 0.f;
#pragma unroll
      for (int nf = 0; nf < 5; ++nf) {
        const float val = acc[mf][nf][r] + b1c[nf];
        const int d = wc * 80 + nf * 16 + r16;
        if (uv == 0) {
          U[j * 320 + d] = val;
          Ub[j * 320 + d] = __float2bfloat16(val);
        } else {
          V[j * 320 + d] = val;
          VbF[((size_t)(j >> 4) * 10 + (d >> 5)) * 512 +
              (((d >> 3) & 3) * 16 + (j & 15)) * 8 + (d & 7)] =
              __float2bfloat16(val);
        }
        s += val;
        q = fmaf(val, val, q);
      }
      const int rw = mf * 16 + g * 4 + r;
      scr[rw * 65 + wc * 16 + r16] = s;
      scr[4160 + rw * 65 + wc * 16 + r16] = q;
    }
  }
  __syncthreads();

  {
    const int r = tid & 63, qq = tid >> 6;
    float s = 0.f, q = 0.f;
#pragma unroll
    for (int k = 0; k < 16; ++k) {
      s += scr[r * 65 + qq * 16 + k];
      q += scr[4160 + r * 65 + qq * 16 + k];
    }
    s4[r][qq] = s;
    q4[r][qq] = q;
  }
  __syncthreads();

  if (tid < 64) {
    const float s = s4[tid][0] + s4[tid][1] + s4[tid][2] + s4[tid][3];
    const float q = q4[tid][0] + q4[tid][1] + q4[tid][2] + q4[tid][3];
    stats[uv * 1024 + i0 + tid] = s;
    stats[uv * 1024 + 512 + i0 + tid] = q;
  }
}

// ---------------------------------------------------------------------------
// Kernel 3: fused, 32-row j-tile for occupancy (LDS ~23.9 KB -> 6 blocks/CU).
// 256 thr / 4 waves. wave w owns 32 rows x cols [w*80,w*80+80): mf=2, nf=5.
// dot on waves 0-1 (MFMA, coalesced VbF). Epilogue scratch aliases dead h1.
// scr f32 map: [0..2079]=s [2080..4159]=q [4160]=s4[32][8] [4416]=q4[32][8]
//              [4672]=e4[32][8] [4928]=rsm[32][2]
// ---------------------------------------------------------------------------
__global__ __launch_bounds__(256, 6) void fused_main(
    const float* __restrict__ U, const float* __restrict__ V,
    const __hip_bfloat16* __restrict__ Ub, const __hip_bfloat16* __restrict__ VbF,
    const __hip_bfloat16* __restrict__ W2F, const float* __restrict__ stats,
    const float* __restrict__ g1, const float* __restrict__ be1,
    const float* __restrict__ b2, const float* __restrict__ g2,
    const float* __restrict__ be2, const float* __restrict__ W3,
    const float* __restrict__ b3, float* __restrict__ out)
{
  __shared__ __align__(16) __hip_bfloat16 h1[32 * 320];   // 20 KB (A / scratch)
  __shared__ __align__(16) float U_lds[320], g1_lds[320], be1_lds[320];
  __shared__ float dt_lds[32];

  const int i   = blockIdx.x;
  const int j0  = blockIdx.y * 32;
  const int tid = threadIdx.x;
  const int lane = tid & 63;
  const int w    = tid >> 6;
  const int r16  = lane & 15;
  const int g    = lane >> 4;
  const int row  = tid >> 3;   // 0..31  (8 threads per row)
  const int seg  = tid & 7;    // 40-elem segment

  // ---- init: stage U row, g1, be1
  for (int t = tid; t < 320; t += 256) {
    U_lds[t]   = U[i * 320 + t];
    g1_lds[t]  = g1[t];
    be1_lds[t] = be1[t];
  }

  // ---- MFMA dot (waves 0-1): j-cols j0 + w*16 + r16, B from VbF coalesced
  if (w < 2) {
    const __hip_bfloat16* __restrict__ Ubrow = Ub + i * 320 + g * 8;
    const __hip_bfloat16* __restrict__ VbFp =
        VbF + ((size_t)((j0 >> 4) + w) * 10) * 512 + lane * 8;
    f32x4 accd = (f32x4){0.f, 0.f, 0.f, 0.f};
#pragma unroll
    for (int kk = 0; kk < 10; ++kk) {
      const bf16x8 da = *(const bf16x8*)(Ubrow + kk * 32);
      const bf16x8 db = *(const bf16x8*)(VbFp + kk * 512);
      accd = __builtin_amdgcn_mfma_f32_16x16x32_bf16(da, db, accd, 0, 0, 0);
    }
    if (lane < 16)
      dt_lds[w * 16 + lane] = accd[0];
  }

  // ---- prologue loads (issued before the barrier)
  const float* __restrict__ Vrow = V + (j0 + row) * 320 + seg * 40;
  f32x4 vreg[10];
#pragma unroll
  for (int m = 0; m < 10; ++m)
    vreg[m] = *(const f32x4*)(Vrow + m * 4);
  const float sVr = stats[1024 + j0 + row];
  const float qVr = stats[1536 + j0 + row];
  const float sU  = stats[i], qU = stats[512 + i];

  const int wc = w;
  const __hip_bfloat16* __restrict__ Bf = W2F + (size_t)(wc * 5) * 512 + lane * 8;
  bf16x8 bbuf[2][5];
#pragma unroll
  for (int nf = 0; nf < 5; ++nf)
    bbuf[0][nf] = *(const bf16x8*)(Bf + nf * 512);

  __syncthreads();

  // ---- P1: LN1 stats (algebraic), elementwise LN1 + leaky -> h1
  const float dt   = dt_lds[row];
  const float mu   = (sU + sVr) * (1.f / 320.f);
  const float var  = (qU + 2.f * dt + qVr) * (1.f / 320.f) - mu * mu;
  const float rs   = rsqrtf(var + LN_EPS);
  const float murs = mu * rs;
  {
    const unsigned swz  = (unsigned)((row & 7) << 4);
    const unsigned base = (unsigned)row * 640u + (unsigned)seg * 80u;
#pragma unroll
    for (int m = 0; m < 5; ++m) {
      const int d = seg * 40 + m * 8;
      const f32x4 va = vreg[2 * m];
      const f32x4 vb = vreg[2 * m + 1];
      const f32x4 ua = *(const f32x4*)&U_lds[d];
      const f32x4 ub = *(const f32x4*)&U_lds[d + 4];
      const f32x4 ga = *(const f32x4*)&g1_lds[d];
      const f32x4 gb = *(const f32x4*)&g1_lds[d + 4];
      const f32x4 ea = *(const f32x4*)&be1_lds[d];
      const f32x4 eb = *(const f32x4*)&be1_lds[d + 4];
      union { bf16x8 v; __hip_bfloat16 e[8]; } pk;
#pragma unroll
      for (int e = 0; e < 4; ++e) {
        const float x = ua[e] + va[e];
        float hv = fmaf(fmaf(x, rs, -murs), ga[e], ea[e]);
        hv = fmaxf(hv, SLOPE * hv);
        pk.e[e] = __float2bfloat16(hv);
      }
#pragma unroll
      for (int e = 0; e < 4; ++e) {
        const float x = ub[e] + vb[e];
        float hv = fmaf(fmaf(x, rs, -murs), gb[e], eb[e]);
        hv = fmaxf(hv, SLOPE * hv);
        pk.e[4 + e] = __float2bfloat16(hv);
      }
      *(bf16x8*)((char*)h1 + ((base + (unsigned)m * 16u) ^ swz)) = pk.v;
    }
  }
  __syncthreads();

  // ---- P2: GEMM. wave w: rows 0..31 (mf=2), cols w*80..+80 (nf=5).
  f32x4 acc[2][5];
#pragma unroll
  for (int mf = 0; mf < 2; ++mf)
#pragma unroll
    for (int nf = 0; nf < 5; ++nf)
      acc[mf][nf] = (f32x4){0.f, 0.f, 0.f, 0.f};

  const unsigned swzA = (unsigned)((r16 & 7) << 4);
  unsigned arow[2];
#pragma unroll
  for (int mf = 0; mf < 2; ++mf)
    arow[mf] = (unsigned)(mf * 16 + r16) * 640u;

#pragma unroll
  for (int kk = 0; kk < 10; ++kk) {
    const int cur = kk & 1, nxt = cur ^ 1;
    if (kk < 9) {
#pragma unroll
      for (int nf = 0; nf < 5; ++nf)
        bbuf[nxt][nf] = *(const bf16x8*)(Bf + ((kk + 1) * 20 + nf) * 512);
    }
    const unsigned k2 = (unsigned)((kk * 32 + g * 8) * 2);
    bf16x8 a[2];
#pragma unroll
    for (int mf = 0; mf < 2; ++mf)
      a[mf] = *(const bf16x8*)((const char*)h1 + ((arow[mf] + k2) ^ swzA));
#pragma unroll
    for (int nf = 0; nf < 5; ++nf)
#pragma unroll
      for (int mf = 0; mf < 2; ++mf)
        acc[mf][nf] = __builtin_amdgcn_mfma_f32_16x16x32_bf16(
            a[mf], bbuf[cur][nf], acc[mf][nf], 0, 0, 0);
  }

  // ---- epilogue params; h2_pre = acc + b2
  float b2c[5], g2c[5], be2c[5], w3c[5];
#pragma unroll
  for (int nf = 0; nf < 5; ++nf) {
    const int col = wc * 80 + nf * 16 + r16;
    b2c[nf]  = b2[col];
    g2c[nf]  = g2[col];
    be2c[nf] = be2[col];
    w3c[nf]  = W3[col];
  }
#pragma unroll
  for (int nf = 0; nf < 5; ++nf)
#pragma unroll
    for (int mf = 0; mf < 2; ++mf)
#pragma unroll
      for (int r = 0; r < 4; ++r)
        acc[mf][nf][r] += b2c[nf];

  // ---- LN2 via LDS partial sums; scr aliases dead h1 (5120 f32)
  float* scr = (float*)h1;
  __syncthreads();           // all GEMM h1 reads complete

  // A: per-lane partials per (mf,r)
#pragma unroll
  for (int mf = 0; mf < 2; ++mf) {
#pragma unroll
    for (int r = 0; r < 4; ++r) {
      float s = 0.f, q = 0.f;
#pragma unroll
      for (int nf = 0; nf < 5; ++nf) {
        const float v = acc[mf][nf][r];
        s += v;
        q = fmaf(v, v, q);
      }
      const int rw = mf * 16 + g * 4 + r;
      scr[rw * 65 + wc * 16 + r16] = s;
      scr[2080 + rw * 65 + wc * 16 + r16] = q;
    }
  }
  __syncthreads();

  // B: 256 threads: row=tid&31, eighth qq=tid>>5 sums 8 partials
  {
    const int r = tid & 31, qq = tid >> 5;
    float s = 0.f, q = 0.f;
#pragma unroll
    for (int k = 0; k < 8; ++k) {
      s += scr[r * 65 + qq * 8 + k];
      q += scr[2080 + r * 65 + qq * 8 + k];
    }
    scr[4160 + r * 8 + qq] = s;
    scr[4416 + r * 8 + qq] = q;
  }
  __syncthreads();

  // C: row stats
  if (tid < 32) {
    float s = 0.f, q = 0.f;
#pragma unroll
    for (int k = 0; k < 8; ++k) {
      s += scr[4160 + tid * 8 + k];
      q += scr[4416 + tid * 8 + k];
    }
    const float mu2  = s * (1.f / 320.f);
    const float var2 = q * (1.f / 320.f) - mu2 * mu2;
    const float rs2  = rsqrtf(var2 + LN_EPS);
    scr[4928 + tid * 2]     = rs2;
    scr[4928 + tid * 2 + 1] = mu2 * rs2;
  }
  __syncthreads();

  // D: apply LN2 + leaky + per-lane W3-dot partial (overwrites s-partials)
#pragma unroll
  for (int mf = 0; mf < 2; ++mf) {
#pragma unroll
    for (int r = 0; r < 4; ++r) {
      const int rw = mf * 16 + g * 4 + r;
      const float rs2 = scr[4928 + rw * 2], murs2 = scr[4928 + rw * 2 + 1];
      float dsum = 0.f;
#pragma unroll
      for (int nf = 0; nf < 5; ++nf) {
        float v = fmaf(fmaf(acc[mf][nf][r], rs2, -murs2), g2c[nf], be2c[nf]);
        v = fmaxf(v, SLOPE * v);
        dsum = fmaf(v, w3c[nf], dsum);
      }
      scr[rw * 65 + wc * 16 + r16] = dsum;
    }
  }
  __syncthreads();

  // E1: eighth sums
  {
    const int r = tid & 31, qq = tid >> 5;
    float s = 0.f;
#pragma unroll
    for (int k = 0; k < 8; ++k)
      s += scr[r * 65 + qq * 8 + k];
    scr[4672 + r * 8 + qq] = s;
  }
  __syncthreads();

  // E2: final
  if (tid < 32) {
    float tot = b3[0];
#pragma unroll
    for (int k = 0; k < 8; ++k)
      tot += scr[4672 + tid * 8 + k];
    out[i * 512 + j0 + tid] = fabsf(tot);
  }
}

// ---------------------------------------------------------------------------
extern "C" void kernel_launch(void* const* d_in, const int* in_sizes, int n_in,
                              void* d_out, int out_size, void* d_ws, size_t ws_size,
                              hipStream_t stream) {
  const float* robot  = (const float*)d_in[0];
  const float* object = (const float*)d_in[1];
  const float* lang   = (const float*)d_in[2];
  const float* W1  = (const float*)d_in[3];
  const float* b1  = (const float*)d_in[4];
  const float* g1  = (const float*)d_in[5];
  const float* be1 = (const float*)d_in[6];
  const float* W2  = (const float*)d_in[7];
  const float* b2  = (const float*)d_in[8];
  const float* g2  = (const float*)d_in[9];
  const float* be2 = (const float*)d_in[10];
  const float* W3  = (const float*)d_in[11];
  const float* b3  = (const float*)d_in[12];
  float* out = (float*)d_out;

  float* U     = (float*)d_ws;            // 512*320 f32
  float* V     = U + 512 * 320;           // 512*320 f32
  float* stats = V + 512 * 320;           // 2048 f32
  __hip_bfloat16* W2F   = (__hip_bfloat16*)(stats + 2048);  // 320*320 bf16
  __hip_bfloat16* Ub    = W2F + 320 * 320;   // 512*320 bf16 (linear)
  __hip_bfloat16* VbF   = Ub + 512 * 320;    // 512*320 bf16 (dot-frag-major)
  __hip_bfloat16* AcatU = VbF + 512 * 320;   // 512*320 bf16
  __hip_bfloat16* AcatV = AcatU + 512 * 320; // 512*320 bf16
  __hip_bfloat16* W1Ft  = AcatV + 512 * 320; // 320*320 bf16 (frag-major)
  __hip_bfloat16* W1Fb  = W1Ft + 320 * 320;  // 320*320 bf16 (frag-major)

  convert_kernel<<<556, 256, 0, stream>>>(robot, object, lang, W1, W2,
                                          AcatU, AcatV, W1Ft, W1Fb, W2F);
  prep_gemm<<<dim3(8, 2), 256, 0, stream>>>(AcatU, AcatV, W1Ft, W1Fb, b1,
                                            U, V, Ub, VbF, stats);
  fused_main<<<dim3(512, 16), 256, 0, stream>>>(U, V, Ub, VbF, W2F, stats,
                                                g1, be1, b2, g2, be2, W3, b3,
                                                out);
}